// Round 1
// baseline (229.383 us; speedup 1.0000x reference)
//
#include <hip/hip_runtime.h>
#include <math.h>

// Problem constants
#define BB 8
#define CC 64
#define HH 128
#define WW 128
#define KK 6

// Workspace layout (float offsets). Total 1,187,904 floats = 4.75 MB.
#define FEAT_OFF 0                      // [B][1024]
#define TH_OFF   8192                   // [B][6]  (sorted angles in radians)
#define COEF_OFF 8256                   // [N=48][C=64][S=2][H=128] = 786432
#define S_OFF    (8256 + 786432)        // [B][64][128][6] = 393216 (post-affine)

// ---------------------------------------------------------------------------
// Kernel 1: adaptive avg-pool 4x4 -> feat[b, c*16 + i*4 + j]
// one block per (b,c); 256 threads; float4 coalesced reads
// ---------------------------------------------------------------------------
__global__ __launch_bounds__(256) void k_pool(const float* __restrict__ x,
                                              float* __restrict__ ws) {
    int bc = blockIdx.x;               // b*64 + c
    int b = bc >> 6, c = bc & 63;
    int t = threadIdx.x;
    __shared__ float pool_l[16];
    if (t < 16) pool_l[t] = 0.f;
    __syncthreads();
    const float4* img4 = (const float4*)(x + (size_t)bc * 16384);
    float acc[4] = {0.f, 0.f, 0.f, 0.f};
    int cb = (t & 31) >> 3;            // W-block (32 float4 per row, 8 per block)
    #pragma unroll
    for (int r = 0; r < 16; ++r) {
        float4 v = img4[r * 256 + t];
        acc[r >> 2] += (v.x + v.y) + (v.z + v.w);   // row-block = r>>2 (exact, t<256)
    }
    #pragma unroll
    for (int rb = 0; rb < 4; ++rb)
        atomicAdd(&pool_l[rb * 4 + cb], acc[rb]);
    __syncthreads();
    if (t < 16)
        ws[FEAT_OFF + b * 1024 + c * 16 + t] = pool_l[t] * (1.0f / 1024.0f);
}

// ---------------------------------------------------------------------------
// Kernel 2: MLP -> offsets -> clip -> sort -> radians. one block per b.
// ---------------------------------------------------------------------------
__global__ __launch_bounds__(256) void k_mlp(const float* __restrict__ lin1_w,
                                             const float* __restrict__ lin1_b,
                                             const float* __restrict__ lin2_w,
                                             const float* __restrict__ lin2_b,
                                             float* __restrict__ ws) {
    int b = blockIdx.x;
    int t = threadIdx.x;
    __shared__ float feat_l[1024];
    __shared__ float h_l[32];
    __shared__ float ang_l[6];
    const float* feat = ws + FEAT_OFF + b * 1024;
    for (int i = t; i < 1024; i += 256) feat_l[i] = feat[i];
    __syncthreads();
    // 8 lanes per output neuron m = t>>3
    int m = t >> 3, part = t & 7;
    const float* wrow = lin1_w + m * 1024 + part * 128;
    const float* frow = feat_l + part * 128;
    float acc = 0.f;
    #pragma unroll 8
    for (int i = 0; i < 128; ++i) acc = fmaf(frow[i], wrow[i], acc);
    acc += __shfl_xor(acc, 1);
    acc += __shfl_xor(acc, 2);
    acc += __shfl_xor(acc, 4);
    if (part == 0) h_l[m] = fmaxf(acc + lin1_b[m], 0.f);
    __syncthreads();
    if (t < 6) {
        float a = lin2_b[t];
        #pragma unroll
        for (int i = 0; i < 32; ++i) a = fmaf(h_l[i], lin2_w[t * 32 + i], a);
        a = 36.0f * (float)t + a * 30.0f;          // base = linspace(0,180,6)
        ang_l[t] = fminf(fmaxf(a, 0.f), 180.f);
    }
    __syncthreads();
    if (t == 0) {
        float v[6];
        #pragma unroll
        for (int i = 0; i < 6; ++i) v[i] = ang_l[i];
        for (int i = 1; i < 6; ++i) {              // insertion sort (ascending)
            float key = v[i]; int j = i - 1;
            while (j >= 0 && v[j] > key) { v[j + 1] = v[j]; --j; }
            v[j + 1] = key;
        }
        #pragma unroll
        for (int i = 0; i < 6; ++i)
            ws[TH_OFF + b * 6 + i] = v[i] * (3.14159265358979323846f / 180.0f);
    }
}

// ---------------------------------------------------------------------------
// Kernel 3: fused Radon (rotate+grid_sample+sum over w) + Wavelet chain.
// One block per (b,c). Image staged in LDS with row stride 129 (bank spread).
// Thread owns a (k,h) line; d(ix)/dw = cos, d(iy)/dw = -sin exactly (AC=True).
// Sinogram lives in LDS; wavelet scratch overlays the (dead) image region.
// ---------------------------------------------------------------------------
__global__ __launch_bounds__(256) void k_radon(const float* __restrict__ x,
                                               const float* __restrict__ wf0,
                                               const float* __restrict__ wf1,
                                               float* __restrict__ ws) {
    int bc = blockIdx.x;
    int b = bc >> 6, c = bc & 63;
    int t = threadIdx.x;
    __shared__ float img[128 * 129];   // 66 KB, stride 129
    __shared__ float sigl[768];        // [k][h]
    __shared__ float co_l[6], si_l[6];

    // stage image (float4 global reads, scalar LDS writes)
    const float4* src4 = (const float4*)(x + (size_t)bc * 16384);
    for (int i = t; i < 4096; i += 256) {
        float4 v = src4[i];
        float* d = img + (i >> 5) * 129 + ((i & 31) << 2);
        d[0] = v.x; d[1] = v.y; d[2] = v.z; d[3] = v.w;
    }
    if (t < 6) {
        float th = ws[TH_OFF + b * 6 + t];
        co_l[t] = cosf(th);
        si_l[t] = sinf(th);
    }
    __syncthreads();

    // --- Radon: 768 (k,h) lines, 3 per thread ---
    for (int p = t; p < 768; p += 256) {
        int k = p >> 7, h = p & 127;
        float co = co_l[k], si = si_l[k];
        float yc = -1.f + (float)h * (2.f / 127.f);
        float ix0 = (fmaf(yc, si, -co) + 1.f) * 63.5f;
        float iy0 = (fmaf(yc, co,  si) + 1.f) * 63.5f;
        float acc = 0.f;
        for (int w = 0; w < 128; ++w) {
            float fw = (float)w;
            float ix = fmaf(fw,  co, ix0);
            float iy = fmaf(fw, -si, iy0);
            float xf = floorf(ix), yf = floorf(iy);
            float wx = ix - xf,  wy = iy - yf;
            int x0 = (int)xf, y0 = (int)yf;
            int x1 = x0 + 1,  y1 = y0 + 1;
            int vx0 = (unsigned)x0 < 128u, vx1 = (unsigned)x1 < 128u;
            int vy0 = (unsigned)y0 < 128u, vy1 = (unsigned)y1 < 128u;
            int xc0 = min(max(x0, 0), 127), xc1 = min(max(x1, 0), 127);
            int r0 = min(max(y0, 0), 127) * 129, r1 = min(max(y1, 0), 127) * 129;
            float v00 = img[r0 + xc0]; v00 = (vx0 & vy0) ? v00 : 0.f;
            float v01 = img[r0 + xc1]; v01 = (vx1 & vy0) ? v01 : 0.f;
            float v10 = img[r1 + xc0]; v10 = (vx0 & vy1) ? v10 : 0.f;
            float v11 = img[r1 + xc1]; v11 = (vx1 & vy1) ? v11 : 0.f;
            float top = fmaf(wx, v01 - v00, v00);
            float bot = fmaf(wx, v11 - v10, v10);
            acc += fmaf(wy, bot - top, top);
        }
        sigl[p] = acc;
    }
    __syncthreads();

    // --- Wavelet chain on sigl (6 rows of 128). Scratch overlays img. ---
    float* cur = img;            // 6*64
    float* f1  = img + 384;      // 6*64
    float* p1  = img + 768;      // 6*32
    float* u1  = img + 960;      // 6*64
    float g0 = wf0[0], g1 = wf0[1], g2 = wf0[2];

    // c0 = conv3(sig), store; cur = avgpool(sig)
    for (int p = t; p < 768; p += 256) {
        int k = p >> 7, h = p & 127;
        const float* s = sigl + k * 128;
        float sm1 = (h > 0)   ? s[h - 1] : 0.f;
        float sp1 = (h < 127) ? s[h + 1] : 0.f;
        float c0 = sm1 * g0 + s[h] * g1 + sp1 * g2;
        ws[COEF_OFF + (((b * 6 + k) * 64 + c) * 2 + 0) * 128 + h] = c0;
    }
    for (int q = t; q < 384; q += 256) {
        int k = q >> 6, l = q & 63;
        cur[q] = (sigl[k * 128 + 2 * l] + sigl[k * 128 + 2 * l + 1]) * 0.5f;
    }
    __syncthreads();

    float w10 = wf1[0], w11 = wf1[1], w12 = wf1[2], w13 = wf1[3], w14 = wf1[4];
    for (int q = t; q < 384; q += 256) {
        int k = q >> 6, l = q & 63;
        const float* cu = cur + k * 64;
        float a = cu[l] * w12;
        a += (l >= 2)  ? cu[l - 2] * w10 : 0.f;
        a += (l >= 1)  ? cu[l - 1] * w11 : 0.f;
        a += (l <= 62) ? cu[l + 1] * w13 : 0.f;
        a += (l <= 61) ? cu[l + 2] * w14 : 0.f;
        f1[q] = a;
    }
    __syncthreads();

    for (int q = t; q < 192; q += 256) {
        int k = q >> 5, m = q & 31;
        p1[q] = (f1[k * 64 + 2 * m] + f1[k * 64 + 2 * m + 1]) * 0.5f;
    }
    __syncthreads();

    for (int q = t; q < 384; q += 256) {    // u1 = interp(p1: 32 -> 64), AC=False
        int k = q >> 6, l = q & 63;
        float real = fminf(fmaxf(0.5f * (float)l - 0.25f, 0.f), 31.f);
        int i0 = (int)real;
        int i1 = min(i0 + 1, 31);
        float wv = real - (float)i0;
        u1[q] = p1[k * 32 + i0] * (1.f - wv) + p1[k * 32 + i1] * wv;
    }
    __syncthreads();

    for (int p = t; p < 768; p += 256) {    // c1 = interp(u1: 64 -> 128), store
        int k = p >> 7, h = p & 127;
        float real = fminf(fmaxf(0.5f * (float)h - 0.25f, 0.f), 63.f);
        int i0 = (int)real;
        int i1 = min(i0 + 1, 63);
        float wv = real - (float)i0;
        float c1 = u1[k * 64 + i0] * (1.f - wv) + u1[k * 64 + i1] * wv;
        ws[COEF_OFF + (((b * 6 + k) * 64 + c) * 2 + 1) * 128 + h] = c1;
    }
}

// ---------------------------------------------------------------------------
// Kernel 4: fusion GEMM hoisted before the k->W interp (linearity), with the
// torch .view permutation undone at LDS staging, and bias+BN affine folded in.
// One block per n=(b,k): S'[o,h2] = affine_o( sum_c2 W[o,c2]*M[c2,h2] ).
// Thread: 8 o-rows x 4 h2-cols; M read as float4, W via 2-addr LDS broadcast.
// ---------------------------------------------------------------------------
__global__ __launch_bounds__(256) void k_fuse(const float* __restrict__ fuse_w,
                                              const float* __restrict__ fuse_b,
                                              const float* __restrict__ bn_gamma,
                                              const float* __restrict__ bn_beta,
                                              const float* __restrict__ bn_mean,
                                              const float* __restrict__ bn_var,
                                              float* __restrict__ ws) {
    int n = blockIdx.x;               // b*6 + k
    int b = n / 6, k = n - b * 6;
    int t = threadIdx.x;
    __shared__ __align__(16) float M[128 * 128];   // 64 KB, M[c2][h2]
    __shared__ float w_l[64 * 128];                // 32 KB
    const float* coef = ws + COEF_OFF + n * 16384;
    for (int i = t; i < 16384; i += 256) {
        int cc = i >> 8, rem = i & 255, s = rem >> 7, hpos = rem & 127;
        int c2 = 2 * cc + (hpos >> 6);
        int h2 = ((hpos & 63) << 1) | s;
        M[c2 * 128 + h2] = coef[i];
        if (i < 8192) w_l[i] = fuse_w[i];
    }
    __syncthreads();

    int hg = t & 31;                  // h2 base = hg*4
    int og = t >> 5;                  // o base = og*8
    float acc[8][4];
    #pragma unroll
    for (int oo = 0; oo < 8; ++oo)
        #pragma unroll
        for (int j = 0; j < 4; ++j) acc[oo][j] = 0.f;

    const float* wbase = w_l + og * 8 * 128;
    for (int c2 = 0; c2 < 128; ++c2) {
        float4 m4 = *(const float4*)(M + c2 * 128 + (hg << 2));
        #pragma unroll
        for (int oo = 0; oo < 8; ++oo) {
            float wv = wbase[oo * 128 + c2];
            acc[oo][0] = fmaf(wv, m4.x, acc[oo][0]);
            acc[oo][1] = fmaf(wv, m4.y, acc[oo][1]);
            acc[oo][2] = fmaf(wv, m4.z, acc[oo][2]);
            acc[oo][3] = fmaf(wv, m4.w, acc[oo][3]);
        }
    }
    #pragma unroll
    for (int oo = 0; oo < 8; ++oo) {
        int o = og * 8 + oo;
        float scale = bn_gamma[o] * rsqrtf(bn_var[o] + 1e-5f);
        float shift = (fuse_b[o] - bn_mean[o]) * scale + bn_beta[o];
        int base = ((b * 64 + o) * 128 + hg * 4) * 6 + k;
        #pragma unroll
        for (int j = 0; j < 4; ++j)
            ws[S_OFF + base + j * 6] = fmaf(acc[oo][j], scale, shift);
    }
}

// ---------------------------------------------------------------------------
// Kernel 5: k(6) -> w(128) align_corners=True interp + ReLU + store.
// (second resize axis is H=128->128, identity per reference's early-out)
// ---------------------------------------------------------------------------
__global__ __launch_bounds__(256) void k_out(const float* __restrict__ S,
                                             float* __restrict__ out) {
    int idx = blockIdx.x * 256 + threadIdx.x;    // (b,o,h2,w)
    int w = idx & 127;
    int row = idx >> 7;                          // (b*64+o)*128 + h2
    float pos = (float)w * (5.0f / 127.0f);
    int i0 = min((int)pos, 5);
    int i1 = min(i0 + 1, 5);
    float tt = pos - (float)i0;
    const float* srow = S + row * 6;
    float val = srow[i0] * (1.f - tt) + srow[i1] * tt;
    out[idx] = fmaxf(val, 0.f);
}

// ---------------------------------------------------------------------------
extern "C" void kernel_launch(void* const* d_in, const int* in_sizes, int n_in,
                              void* d_out, int out_size, void* d_ws, size_t ws_size,
                              hipStream_t stream) {
    const float* x        = (const float*)d_in[0];
    const float* lin1_w   = (const float*)d_in[1];
    const float* lin1_b   = (const float*)d_in[2];
    const float* lin2_w   = (const float*)d_in[3];
    const float* lin2_b   = (const float*)d_in[4];
    const float* wf0      = (const float*)d_in[5];
    const float* wf1      = (const float*)d_in[6];
    const float* fuse_w   = (const float*)d_in[7];
    const float* fuse_b   = (const float*)d_in[8];
    const float* bn_gamma = (const float*)d_in[9];
    const float* bn_beta  = (const float*)d_in[10];
    const float* bn_mean  = (const float*)d_in[11];
    const float* bn_var   = (const float*)d_in[12];
    float* ws  = (float*)d_ws;        // needs 4.75 MB
    float* out = (float*)d_out;

    hipLaunchKernelGGL(k_pool,  dim3(BB * CC), dim3(256), 0, stream, x, ws);
    hipLaunchKernelGGL(k_mlp,   dim3(BB),      dim3(256), 0, stream,
                       lin1_w, lin1_b, lin2_w, lin2_b, ws);
    hipLaunchKernelGGL(k_radon, dim3(BB * CC), dim3(256), 0, stream, x, wf0, wf1, ws);
    hipLaunchKernelGGL(k_fuse,  dim3(BB * KK), dim3(256), 0, stream,
                       fuse_w, fuse_b, bn_gamma, bn_beta, bn_mean, bn_var, ws);
    hipLaunchKernelGGL(k_out,   dim3((BB * CC * HH * WW) / 256), dim3(256), 0, stream,
                       ws + S_OFF, out);
}

// Round 2
// 183.445 us; speedup vs baseline: 1.2504x; 1.2504x over previous
//
#include <hip/hip_runtime.h>
#include <math.h>

// Problem constants
#define BB 8
#define CC 64
#define HH 128
#define WW 128
#define KK 6

// Workspace layout (float offsets). Total 1,187,904 floats = 4.75 MB.
#define FEAT_OFF 0                      // [B][1024]
#define TH_OFF   8192                   // [B][6]  (sorted angles in radians)
#define COEF_OFF 8256                   // [N=48][C=64][S=2][H=128] = 786432
#define S_OFF    (8256 + 786432)        // [B][64][128][6] = 393216 (post-affine)

// ---------------------------------------------------------------------------
// Kernel 1: adaptive avg-pool 4x4 -> feat[b, c*16 + i*4 + j]
// ---------------------------------------------------------------------------
__global__ __launch_bounds__(256) void k_pool(const float* __restrict__ x,
                                              float* __restrict__ ws) {
    int bc = blockIdx.x;               // b*64 + c
    int b = bc >> 6, c = bc & 63;
    int t = threadIdx.x;
    __shared__ float pool_l[16];
    if (t < 16) pool_l[t] = 0.f;
    __syncthreads();
    const float4* img4 = (const float4*)(x + (size_t)bc * 16384);
    float acc[4] = {0.f, 0.f, 0.f, 0.f};
    int cb = (t & 31) >> 3;            // W-block (32 float4 per row, 8 per block)
    #pragma unroll
    for (int r = 0; r < 16; ++r) {
        float4 v = img4[r * 256 + t];
        acc[r >> 2] += (v.x + v.y) + (v.z + v.w);
    }
    #pragma unroll
    for (int rb = 0; rb < 4; ++rb)
        atomicAdd(&pool_l[rb * 4 + cb], acc[rb]);
    __syncthreads();
    if (t < 16)
        ws[FEAT_OFF + b * 1024 + c * 16 + t] = pool_l[t] * (1.0f / 1024.0f);
}

// ---------------------------------------------------------------------------
// Kernel 2: MLP -> offsets -> clip -> sort -> radians. one block per b.
// ---------------------------------------------------------------------------
__global__ __launch_bounds__(256) void k_mlp(const float* __restrict__ lin1_w,
                                             const float* __restrict__ lin1_b,
                                             const float* __restrict__ lin2_w,
                                             const float* __restrict__ lin2_b,
                                             float* __restrict__ ws) {
    int b = blockIdx.x;
    int t = threadIdx.x;
    __shared__ float feat_l[1024];
    __shared__ float h_l[32];
    __shared__ float ang_l[6];
    const float* feat = ws + FEAT_OFF + b * 1024;
    for (int i = t; i < 1024; i += 256) feat_l[i] = feat[i];
    __syncthreads();
    int m = t >> 3, part = t & 7;
    const float* wrow = lin1_w + m * 1024 + part * 128;
    const float* frow = feat_l + part * 128;
    float acc = 0.f;
    #pragma unroll 8
    for (int i = 0; i < 128; ++i) acc = fmaf(frow[i], wrow[i], acc);
    acc += __shfl_xor(acc, 1);
    acc += __shfl_xor(acc, 2);
    acc += __shfl_xor(acc, 4);
    if (part == 0) h_l[m] = fmaxf(acc + lin1_b[m], 0.f);
    __syncthreads();
    if (t < 6) {
        float a = lin2_b[t];
        #pragma unroll
        for (int i = 0; i < 32; ++i) a = fmaf(h_l[i], lin2_w[t * 32 + i], a);
        a = 36.0f * (float)t + a * 30.0f;          // base = linspace(0,180,6)
        ang_l[t] = fminf(fmaxf(a, 0.f), 180.f);
    }
    __syncthreads();
    if (t == 0) {
        float v[6];
        #pragma unroll
        for (int i = 0; i < 6; ++i) v[i] = ang_l[i];
        for (int i = 1; i < 6; ++i) {              // insertion sort
            float key = v[i]; int j = i - 1;
            while (j >= 0 && v[j] > key) { v[j + 1] = v[j]; --j; }
            v[j + 1] = key;
        }
        #pragma unroll
        for (int i = 0; i < 6; ++i)
            ws[TH_OFF + b * 6 + i] = v[i] * (3.14159265358979323846f / 180.0f);
    }
}

// ---------------------------------------------------------------------------
// Kernel 3: fused Radon + Wavelet.
// Image in LDS with a ZERO BORDER: rows/cols -1..128, stride 130. Out-of-range
// bilinear taps hit the zero pad (== padding_mode='zeros'), so the inner loop
// has NO masks/clamps. Per (k,h) line, the nonzero-w set is a convex interval
// [wA,wB) computed by slab test + endpoint verify; outside it, sample == 0.
// Stride 130: per-lane bank drift = 2*co+si (worst ~0.33 at 108deg => ~3-way,
// vs stride 129's co+si -> 0 at 135-144deg => 4-5-way clustering).
// ---------------------------------------------------------------------------
__global__ __launch_bounds__(256) void k_radon(const float* __restrict__ x,
                                               const float* __restrict__ wf0,
                                               const float* __restrict__ wf1,
                                               float* __restrict__ ws) {
    int bc = blockIdx.x;
    int b = bc >> 6, c = bc & 63;
    int t = threadIdx.x;
    __shared__ float imgp[130 * 130];  // 67.6 KB padded image
    __shared__ float sigl[768];        // [k][h]
    __shared__ float co_l[6], si_l[6];

    // zero the 1-px border (rows 0,129 and cols 0,129)
    for (int i = t; i < 130; i += 256) {
        imgp[i] = 0.f;
        imgp[129 * 130 + i] = 0.f;
        imgp[i * 130] = 0.f;
        imgp[i * 130 + 129] = 0.f;
    }
    // stage interior: (y,x) -> imgp[(y+1)*130 + (x+1)]
    const float4* src4 = (const float4*)(x + (size_t)bc * 16384);
    for (int i = t; i < 4096; i += 256) {
        float4 v = src4[i];
        float* d = imgp + ((i >> 5) + 1) * 130 + ((i & 31) << 2) + 1;
        d[0] = v.x; d[1] = v.y; d[2] = v.z; d[3] = v.w;
    }
    if (t < 6) {
        float th = ws[TH_OFF + b * 6 + t];
        co_l[t] = cosf(th);
        si_l[t] = sinf(th);
    }
    __syncthreads();

    const float* base = imgp + 131;    // (y,x) -> base[y*130 + x], y,x in [-1,128]
    const float LO = -0.9999f, HIA = 127.9999f;

    for (int p = t; p < 768; p += 256) {
        int k = p >> 7, h = p & 127;
        float co = co_l[k], si = si_l[k];
        float yc = fmaf((float)h, 2.0f / 127.0f, -1.0f);
        float ix0 = (fmaf(yc, si, -co) + 1.0f) * 63.5f;  // d(ix)/dw = co exactly
        float iy0 = (fmaf(yc, co,  si) + 1.0f) * 63.5f;  // d(iy)/dw = -si exactly

        // slab test for { w : ix in [LO,HIA] and iy in [LO,HIA] }
        float ic = 1.0f / co, is = 1.0f / (-si);
        float a1 = (LO - ix0) * ic, a2 = (HIA - ix0) * ic;
        float b1 = (LO - iy0) * is, b2 = (HIA - iy0) * is;
        float wlo = fmaxf(fmaxf(fminf(a1, a2), fminf(b1, b2)), 0.0f);
        float whi = fminf(fminf(fmaxf(a1, a2), fmaxf(b1, b2)), 127.0f);
        int wA = (int)ceilf(wlo);
        int wB = (int)floorf(whi) + 1;
        wA = max(0, min(wA, 128));
        wB = max(wA, min(wB, 128));
        // endpoint verification: predicate set is a convex integer interval,
        // so interior endpoints => whole range safe (NaN/rounding-proof).
        while (wA < wB) {
            float ix = fmaf((float)wA, co, ix0), iy = fmaf((float)wA, -si, iy0);
            if (ix >= LO && ix <= HIA && iy >= LO && iy <= HIA) break;
            ++wA;
        }
        while (wB > wA) {
            float ix = fmaf((float)(wB - 1), co, ix0), iy = fmaf((float)(wB - 1), -si, iy0);
            if (ix >= LO && ix <= HIA && iy >= LO && iy <= HIA) break;
            --wB;
        }

        float acc = 0.f;
        for (int w = wA; w < wB; ++w) {
            float fw = (float)w;
            float ix = fmaf(fw,  co, ix0);
            float iy = fmaf(fw, -si, iy0);
            float xf = floorf(ix), yf = floorf(iy);
            float wx = ix - xf, wy = iy - yf;
            int x0 = (int)xf, y0 = (int)yf;
            const float* q = base + y0 * 130 + x0;
            float v00 = q[0], v01 = q[1];          // ds_read2_b32
            float v10 = q[130], v11 = q[131];      // ds_read2_b32
            float top = fmaf(wx, v01 - v00, v00);
            float bot = fmaf(wx, v11 - v10, v10);
            acc += fmaf(wy, bot - top, top);
        }
        sigl[p] = acc;
    }
    __syncthreads();

    // --- Wavelet chain on sigl (6 rows of 128). Scratch overlays imgp. ---
    float* cur = imgp;           // 6*64
    float* f1  = imgp + 384;     // 6*64
    float* p1  = imgp + 768;     // 6*32
    float* u1  = imgp + 960;     // 6*64
    float g0 = wf0[0], g1 = wf0[1], g2 = wf0[2];

    for (int p = t; p < 768; p += 256) {           // c0 = conv3(sig)
        int k = p >> 7, h = p & 127;
        const float* s = sigl + k * 128;
        float sm1 = (h > 0)   ? s[h - 1] : 0.f;
        float sp1 = (h < 127) ? s[h + 1] : 0.f;
        float c0 = sm1 * g0 + s[h] * g1 + sp1 * g2;
        ws[COEF_OFF + (((b * 6 + k) * 64 + c) * 2 + 0) * 128 + h] = c0;
    }
    for (int q = t; q < 384; q += 256) {           // cur = avgpool(sig)
        int k = q >> 6, l = q & 63;
        cur[q] = (sigl[k * 128 + 2 * l] + sigl[k * 128 + 2 * l + 1]) * 0.5f;
    }
    __syncthreads();

    float w10 = wf1[0], w11 = wf1[1], w12 = wf1[2], w13 = wf1[3], w14 = wf1[4];
    for (int q = t; q < 384; q += 256) {           // f1 = conv5(cur)
        int k = q >> 6, l = q & 63;
        const float* cu = cur + k * 64;
        float a = cu[l] * w12;
        a += (l >= 2)  ? cu[l - 2] * w10 : 0.f;
        a += (l >= 1)  ? cu[l - 1] * w11 : 0.f;
        a += (l <= 62) ? cu[l + 1] * w13 : 0.f;
        a += (l <= 61) ? cu[l + 2] * w14 : 0.f;
        f1[q] = a;
    }
    __syncthreads();

    for (int q = t; q < 192; q += 256) {           // p1 = avgpool(f1)
        int k = q >> 5, m = q & 31;
        p1[q] = (f1[k * 64 + 2 * m] + f1[k * 64 + 2 * m + 1]) * 0.5f;
    }
    __syncthreads();

    for (int q = t; q < 384; q += 256) {           // u1 = interp(p1: 32->64), AC=False
        int k = q >> 6, l = q & 63;
        float real = fminf(fmaxf(0.5f * (float)l - 0.25f, 0.f), 31.f);
        int i0 = (int)real;
        int i1 = min(i0 + 1, 31);
        float wv = real - (float)i0;
        u1[q] = p1[k * 32 + i0] * (1.f - wv) + p1[k * 32 + i1] * wv;
    }
    __syncthreads();

    for (int p = t; p < 768; p += 256) {           // c1 = interp(u1: 64->128)
        int k = p >> 7, h = p & 127;
        float real = fminf(fmaxf(0.5f * (float)h - 0.25f, 0.f), 63.f);
        int i0 = (int)real;
        int i1 = min(i0 + 1, 63);
        float wv = real - (float)i0;
        float c1 = u1[k * 64 + i0] * (1.f - wv) + u1[k * 64 + i1] * wv;
        ws[COEF_OFF + (((b * 6 + k) * 64 + c) * 2 + 1) * 128 + h] = c1;
    }
}

// ---------------------------------------------------------------------------
// Kernel 4: fusion GEMM hoisted before the k->W interp (linearity), permutation
// undone at staging, bias+BN folded. Split 4x over output channels for
// parallelism: grid = 48*4 blocks (was 48 -> used only 48 of 256 CUs).
// Block (n, quarter q): S'[o,h2] for o in [16q,16q+16), all 128 h2.
// ---------------------------------------------------------------------------
__global__ __launch_bounds__(256) void k_fuse(const float* __restrict__ fuse_w,
                                              const float* __restrict__ fuse_b,
                                              const float* __restrict__ bn_gamma,
                                              const float* __restrict__ bn_beta,
                                              const float* __restrict__ bn_mean,
                                              const float* __restrict__ bn_var,
                                              float* __restrict__ ws) {
    int blk = blockIdx.x;
    int n = blk >> 2, q = blk & 3;    // n = b*6 + k
    int b = n / 6, k = n - b * 6;
    int t = threadIdx.x;
    __shared__ __align__(16) float M[128 * 128];   // 64 KB, M[c2][h2]
    __shared__ float w_l[16 * 128];                // 8 KB
    const float* coef = ws + COEF_OFF + n * 16384;
    for (int i = t; i < 16384; i += 256) {
        int cc = i >> 8, rem = i & 255, s = rem >> 7, hpos = rem & 127;
        int c2 = 2 * cc + (hpos >> 6);
        int h2 = ((hpos & 63) << 1) | s;
        M[c2 * 128 + h2] = coef[i];
    }
    for (int i = t; i < 2048; i += 256)
        w_l[i] = fuse_w[(q * 16 + (i >> 7)) * 128 + (i & 127)];
    __syncthreads();

    int hg = t & 31;                  // h2 base = hg*4
    int og = t >> 5;                  // o pair index 0..7
    float acc[2][4];
    #pragma unroll
    for (int oo = 0; oo < 2; ++oo)
        #pragma unroll
        for (int j = 0; j < 4; ++j) acc[oo][j] = 0.f;

    const float* w0 = w_l + (og * 2) * 128;
    const float* w1 = w0 + 128;
    for (int c2 = 0; c2 < 128; ++c2) {
        float4 m4 = *(const float4*)(M + c2 * 128 + (hg << 2));
        float a0 = w0[c2], a1 = w1[c2];
        acc[0][0] = fmaf(a0, m4.x, acc[0][0]);
        acc[0][1] = fmaf(a0, m4.y, acc[0][1]);
        acc[0][2] = fmaf(a0, m4.z, acc[0][2]);
        acc[0][3] = fmaf(a0, m4.w, acc[0][3]);
        acc[1][0] = fmaf(a1, m4.x, acc[1][0]);
        acc[1][1] = fmaf(a1, m4.y, acc[1][1]);
        acc[1][2] = fmaf(a1, m4.z, acc[1][2]);
        acc[1][3] = fmaf(a1, m4.w, acc[1][3]);
    }
    #pragma unroll
    for (int oo = 0; oo < 2; ++oo) {
        int o = q * 16 + og * 2 + oo;
        float scale = bn_gamma[o] * rsqrtf(bn_var[o] + 1e-5f);
        float shift = (fuse_b[o] - bn_mean[o]) * scale + bn_beta[o];
        int basei = ((b * 64 + o) * 128 + hg * 4) * 6 + k;
        #pragma unroll
        for (int j = 0; j < 4; ++j)
            ws[S_OFF + basei + j * 6] = fmaf(acc[oo][j], scale, shift);
    }
}

// ---------------------------------------------------------------------------
// Kernel 5: k(6) -> w(128) align_corners=True interp + ReLU + store.
// ---------------------------------------------------------------------------
__global__ __launch_bounds__(256) void k_out(const float* __restrict__ S,
                                             float* __restrict__ out) {
    int idx = blockIdx.x * 256 + threadIdx.x;    // (b,o,h2,w)
    int w = idx & 127;
    int row = idx >> 7;
    float pos = (float)w * (5.0f / 127.0f);
    int i0 = min((int)pos, 5);
    int i1 = min(i0 + 1, 5);
    float tt = pos - (float)i0;
    const float* srow = S + row * 6;
    float val = srow[i0] * (1.f - tt) + srow[i1] * tt;
    out[idx] = fmaxf(val, 0.f);
}

// ---------------------------------------------------------------------------
extern "C" void kernel_launch(void* const* d_in, const int* in_sizes, int n_in,
                              void* d_out, int out_size, void* d_ws, size_t ws_size,
                              hipStream_t stream) {
    const float* x        = (const float*)d_in[0];
    const float* lin1_w   = (const float*)d_in[1];
    const float* lin1_b   = (const float*)d_in[2];
    const float* lin2_w   = (const float*)d_in[3];
    const float* lin2_b   = (const float*)d_in[4];
    const float* wf0      = (const float*)d_in[5];
    const float* wf1      = (const float*)d_in[6];
    const float* fuse_w   = (const float*)d_in[7];
    const float* fuse_b   = (const float*)d_in[8];
    const float* bn_gamma = (const float*)d_in[9];
    const float* bn_beta  = (const float*)d_in[10];
    const float* bn_mean  = (const float*)d_in[11];
    const float* bn_var   = (const float*)d_in[12];
    float* ws  = (float*)d_ws;        // needs 4.75 MB
    float* out = (float*)d_out;

    hipLaunchKernelGGL(k_pool,  dim3(BB * CC), dim3(256), 0, stream, x, ws);
    hipLaunchKernelGGL(k_mlp,   dim3(BB),      dim3(256), 0, stream,
                       lin1_w, lin1_b, lin2_w, lin2_b, ws);
    hipLaunchKernelGGL(k_radon, dim3(BB * CC), dim3(256), 0, stream, x, wf0, wf1, ws);
    hipLaunchKernelGGL(k_fuse,  dim3(BB * KK * 4), dim3(256), 0, stream,
                       fuse_w, fuse_b, bn_gamma, bn_beta, bn_mean, bn_var, ws);
    hipLaunchKernelGGL(k_out,   dim3((BB * CC * HH * WW) / 256), dim3(256), 0, stream,
                       ws + S_OFF, out);
}